// Round 14
// baseline (69.327 us; speedup 1.0000x reference)
//
#include <hip/hip_runtime.h>
#include <hip/hip_bf16.h>

#define BATCH 8
#define CIN   64
#define COUT  64
#define HH    128
#define WW    128
#define HW    (HH * WW)
#define OFFC  18
#define KK    9
#define NROWS 7
#define ROWB  (WW * 128)          // 16384 B per staged row (128 px x 128 B)

typedef __attribute__((ext_vector_type(8))) short short8;
typedef __attribute__((ext_vector_type(8))) unsigned short ushort8;
typedef __attribute__((ext_vector_type(4))) float f32x4;

__device__ __forceinline__ float bf2f(unsigned short u) {
    return __builtin_bit_cast(float, ((unsigned int)u) << 16);
}
__device__ __forceinline__ short f2bf(float v) {
    __hip_bfloat16 h = __float2bfloat16(v);
    return __builtin_bit_cast(short, h);
}

// ------- Kernel X: x (b,c,h,w) f32 -> xT (b,h,w,c) bf16 -------
__global__ __launch_bounds__(256) void to_chlast_k(
    const float* __restrict__ x, unsigned short* __restrict__ xT)
{
    __shared__ unsigned short t[128 * 72];
    int blk = blockIdx.x;                    // ho*8 + b
    int b  = blk & 7;
    int ho = blk >> 3;
    int tid = threadIdx.x;

    const float* xr = x + (size_t)b * CIN * HW + ho * WW;
    for (int i = tid; i < 2048; i += 256) {
        int c = i >> 5, w4 = (i & 31) * 4;
        float4 v = *(const float4*)(xr + (size_t)c * HW + w4);
        t[(w4 + 0) * 72 + c] = (unsigned short)f2bf(v.x);
        t[(w4 + 1) * 72 + c] = (unsigned short)f2bf(v.y);
        t[(w4 + 2) * 72 + c] = (unsigned short)f2bf(v.z);
        t[(w4 + 3) * 72 + c] = (unsigned short)f2bf(v.w);
    }
    __syncthreads();

    unsigned short* orow = xT + (size_t)(b * HH + ho) * WW * 64;
    for (int j = tid; j < 1024; j += 256) {
        int w = j >> 3, c8 = (j & 7) * 8;
        *(ushort8*)(orow + w * 64 + c8) = *(const ushort8*)(t + w * 72 + c8);
    }
}

// ------- Kernel B: w_deform -> bf16 B-fragments wf[kk][nt(4)][lane][8] -------
__global__ __launch_bounds__(256) void build_wfrag_k(
    const float* __restrict__ wd, unsigned short* __restrict__ wf)
{
    int idx = blockIdx.x * 256 + threadIdx.x;
    int ck = idx % 576;
    int o  = idx / 576;
    int c = ck & 63, k = ck >> 6;
    float v = wd[o * 576 + c * 9 + k];
    int kk = ck >> 5, nt = o >> 4;
    int lane = (o & 15) | (((ck >> 3) & 3) << 4);
    int j = ck & 7;
    wf[((kk * 4 + nt) * 64 + lane) * 8 + j] = (unsigned short)f2bf(v);
}

// ------- Kernel B2: w_offset -> bf16 B-fragments wfo[kk][nt(2)][lane][8], N pad 18->32 -------
__global__ __launch_bounds__(256) void build_wfo_k(
    const float* __restrict__ wo, unsigned short* __restrict__ wfo)
{
    int idx = blockIdx.x * 256 + threadIdx.x;
    if (idx >= 32 * 576) return;
    int ck = idx % 576;
    int ov = idx / 576;
    int c = ck & 63, tap = ck >> 6;
    float v = (ov < OFFC) ? wo[ov * 576 + c * 9 + tap] : 0.f;
    int kk = ck >> 5, nt = ov >> 4;
    int lane = (ov & 15) | (((ck >> 3) & 3) << 4);
    int j = ck & 7;
    wfo[((kk * 2 + nt) * 64 + lane) * 8 + j] = (unsigned short)f2bf(v);
}

// ---------------- Kernel C: LDS-staged gather, 2-row/512-thr, de-phased + precomputed ----------------
// R13 + two critical-path cuts:
// (1) ALL position work (bilinear weights f32 + packed corner idx) precomputed into
//     statically-indexed VGPRs before the tap loop -> tap loop is pure
//     {wf load, unpack, ds_read x16, interp, MFMA} with addresses ready up-front.
// (2) Wave de-phasing: row-group 1 (waves 4-7) runs taps rotated by 4 (phase A by 9).
//     SIMD-paired waves (w, w+4) sit 4 taps apart -> one's wf/ds latency hides under
//     the other's interp; waves WITHIN a group stay aligned (wf L1 sharing kept).
//     Rotation only permutes fp accumulation order (margin 0.031 vs 0.088).
__global__ __launch_bounds__(512, 2) void deform_fused6_k(
    const unsigned short* __restrict__ xT,
    const short8* __restrict__ wfo,
    const short8* __restrict__ wf, float* __restrict__ out)
{
    __shared__ char  stage[NROWS * ROWB];   // 114688 B
    __shared__ float offsL[8][32 * 20];     // 20480 B  (total 135168 B)

    int tid  = threadIdx.x;
    int blk  = blockIdx.x;                  // rowpair*8 + b
    int b    = blk & 7;
    int ho0  = (blk >> 3) * 2;
    int row_lo = ho0 - 2;                   // staged rows row_lo .. row_lo+6

    const unsigned short* pT = xT + (size_t)b * HW * 64;

    int lane  = tid & 63;
    int wave  = tid >> 6;                   // 0..7
    int wl    = wave & 3;
    int grp   = wave >> 2;                  // row group 0/1
    int ho    = ho0 + grp;
    int prow  = lane & 15;
    int khalf = lane >> 4;
    int px0   = wl * 32 + prow;
    int px1   = px0 + 16;

    // ---- STAGE: rows row_lo..row_lo+6 of xT[b] -> swizzled LDS (512 threads) ----
    for (int c = tid; c < NROWS * 1024; c += 512) {
        int r  = c >> 10;
        int ar = row_lo + r;
        if ((unsigned)ar < (unsigned)HH) {
            int px   = (c >> 3) & 127;
            int slot = c & 7;
            ushort8 v = *(const ushort8*)(pT + (((size_t)ar * WW + px) << 6) + slot * 8);
            *(ushort8*)(stage + r * ROWB + px * 128 + ((slot ^ (px & 7)) << 4)) = v;
        }
    }
    __syncthreads();

    auto LRD = [&](int r, int xc, int slot) -> ushort8 {
        return *(const ushort8*)(stage + r * ROWB + xc * 128 + ((slot ^ (xc & 7)) << 4));
    };
    auto GRD = [&](int idx, int h) -> ushort8 {
        return *(const ushort8*)(pT + ((size_t)idx << 6) + (khalf << 3) + h * 32);
    };

    // ---- phase A: offsets conv via MFMA from the stage (kk rotated by grp*9) ----
    {
        f32x4 oa00 = {0.f,0.f,0.f,0.f}, oa01 = {0.f,0.f,0.f,0.f};
        f32x4 oa10 = {0.f,0.f,0.f,0.f}, oa11 = {0.f,0.f,0.f,0.f};
        int rotA = grp * 9;
        #pragma unroll
        for (int k0 = 0; k0 < 18; ++k0) {
            int kk = k0 + rotA; if (kk >= 18) kk -= 18;   // runtime addr arith only
            int tap = kk >> 1;
            int y   = ho + tap / 3 - 1;
            int dx  = tap % 3 - 1;
            int slot = khalf + (kk & 1) * 4;
            short8 a0 = {0,0,0,0,0,0,0,0};
            short8 a1 = {0,0,0,0,0,0,0,0};
            int xw0 = px0 + dx, xw1 = px1 + dx;
            if ((unsigned)y < HH) {
                int ry = y - row_lo;        // in [1,4], always staged
                if ((unsigned)xw0 < WW) a0 = __builtin_bit_cast(short8, LRD(ry, xw0, slot));
                if ((unsigned)xw1 < WW) a1 = __builtin_bit_cast(short8, LRD(ry, xw1, slot));
            }
            short8 b0 = wfo[(kk * 2 + 0) * 64 + lane];
            short8 b1 = wfo[(kk * 2 + 1) * 64 + lane];
            oa00 = __builtin_amdgcn_mfma_f32_16x16x32_bf16(a0, b0, oa00, 0, 0, 0);
            oa01 = __builtin_amdgcn_mfma_f32_16x16x32_bf16(a0, b1, oa01, 0, 0, 0);
            oa10 = __builtin_amdgcn_mfma_f32_16x16x32_bf16(a1, b0, oa10, 0, 0, 0);
            oa11 = __builtin_amdgcn_mfma_f32_16x16x32_bf16(a1, b1, oa11, 0, 0, 0);
        }
        int ocol = lane & 15;
        int pl0  = khalf * 4;
        #pragma unroll
        for (int r = 0; r < 4; ++r) {
            offsL[wave][(pl0 + r) * 20 + ocol]      = oa00[r];
            offsL[wave][(pl0 + 16 + r) * 20 + ocol] = oa10[r];
        }
        if (ocol < 2) {
            #pragma unroll
            for (int r = 0; r < 4; ++r) {
                offsL[wave][(pl0 + r) * 20 + 16 + ocol]      = oa01[r];
                offsL[wave][(pl0 + 16 + r) * 20 + 16 + ocol] = oa11[r];
            }
        }
    }
    // no barrier: offsL slice is wave-private

    // ---- PRECOMPUTE: all 9 taps x 2 tiles -> packed corner idx + f32 weights (static regs) ----
    int   rotT = grp * 4;
    float4 wtA[9], wtB[9];
    int    pkA[9], pkB[9];
    #pragma unroll
    for (int s = 0; s < 9; ++s) {
        int t = s + rotT; if (t >= 9) t -= 9;             // runtime tap id (addr arith only)
        int ty = t / 3 - 1, tx = t % 3 - 1;
        // tile A
        {
            float dy = offsL[wave][prow * 20 + 2 * t];
            float dx = offsL[wave][prow * 20 + 2 * t + 1];
            float yy = (float)(ho + ty) + dy;
            float xx = (float)(px0 + tx) + dx;
            float y0 = floorf(yy), x0 = floorf(xx);
            float wy1 = yy - y0, wx1 = xx - x0;
            float wy0 = 1.f - wy1, wx0 = 1.f - wx1;
            bool valid = (yy > -1.f) && (yy < (float)HH) && (xx > -1.f) && (xx < (float)WW);
            int y0i = (int)y0, x0i = (int)x0;
            bool iy0 = (unsigned)y0i < HH, iy1 = (unsigned)(y0i + 1) < HH;
            bool ix0 = (unsigned)x0i < WW, ix1 = (unsigned)(x0i + 1) < WW;
            float m00 = (valid && iy0 && ix0) ? 1.f : 0.f;
            float m01 = (valid && iy0 && ix1) ? 1.f : 0.f;
            float m10 = (valid && iy1 && ix0) ? 1.f : 0.f;
            float m11 = (valid && iy1 && ix1) ? 1.f : 0.f;
            int yc0 = min(max(y0i, 0), HH - 1), yc1 = min(max(y0i + 1, 0), HH - 1);
            int xc0 = min(max(x0i, 0), WW - 1), xc1 = min(max(x0i + 1, 0), WW - 1);
            wtA[s] = make_float4(wy0 * wx0 * m00, wy0 * wx1 * m01, wy1 * wx0 * m10, wy1 * wx1 * m11);
            pkA[s] = (yc0 * WW + xc0) | ((xc1 - xc0) << 14) | ((yc1 - yc0) << 15);
        }
        // tile B
        {
            float dy = offsL[wave][(prow + 16) * 20 + 2 * t];
            float dx = offsL[wave][(prow + 16) * 20 + 2 * t + 1];
            float yy = (float)(ho + ty) + dy;
            float xx = (float)(px1 + tx) + dx;
            float y0 = floorf(yy), x0 = floorf(xx);
            float wy1 = yy - y0, wx1 = xx - x0;
            float wy0 = 1.f - wy1, wx0 = 1.f - wx1;
            bool valid = (yy > -1.f) && (yy < (float)HH) && (xx > -1.f) && (xx < (float)WW);
            int y0i = (int)y0, x0i = (int)x0;
            bool iy0 = (unsigned)y0i < HH, iy1 = (unsigned)(y0i + 1) < HH;
            bool ix0 = (unsigned)x0i < WW, ix1 = (unsigned)(x0i + 1) < WW;
            float m00 = (valid && iy0 && ix0) ? 1.f : 0.f;
            float m01 = (valid && iy0 && ix1) ? 1.f : 0.f;
            float m10 = (valid && iy1 && ix0) ? 1.f : 0.f;
            float m11 = (valid && iy1 && ix1) ? 1.f : 0.f;
            int yc0 = min(max(y0i, 0), HH - 1), yc1 = min(max(y0i + 1, 0), HH - 1);
            int xc0 = min(max(x0i, 0), WW - 1), xc1 = min(max(x0i + 1, 0), WW - 1);
            wtB[s] = make_float4(wy0 * wx0 * m00, wy0 * wx1 * m01, wy1 * wx0 * m10, wy1 * wx1 * m11);
            pkB[s] = (yc0 * WW + xc0) | ((xc1 - xc0) << 14) | ((yc1 - yc0) << 15);
        }
    }

    // ---- tap loop: pure gather + interp + MFMA (tap order rotated by grp*4) ----
    f32x4 accA0 = {0.f,0.f,0.f,0.f}, accA1 = {0.f,0.f,0.f,0.f};
    f32x4 accA2 = {0.f,0.f,0.f,0.f}, accA3 = {0.f,0.f,0.f,0.f};
    f32x4 accB0 = {0.f,0.f,0.f,0.f}, accB1 = {0.f,0.f,0.f,0.f};
    f32x4 accB2 = {0.f,0.f,0.f,0.f}, accB3 = {0.f,0.f,0.f,0.f};

    #pragma unroll
    for (int s = 0; s < 9; ++s) {
        int t = s + rotT; if (t >= 9) t -= 9;             // for wf addressing only

        short8 b00 = wf[((2 * t) * 4 + 0) * 64 + lane];
        short8 b01 = wf[((2 * t) * 4 + 1) * 64 + lane];
        short8 b02 = wf[((2 * t) * 4 + 2) * 64 + lane];
        short8 b03 = wf[((2 * t) * 4 + 3) * 64 + lane];
        short8 b10 = wf[((2 * t + 1) * 4 + 0) * 64 + lane];
        short8 b11 = wf[((2 * t + 1) * 4 + 1) * 64 + lane];
        short8 b12 = wf[((2 * t + 1) * 4 + 2) * 64 + lane];
        short8 b13 = wf[((2 * t + 1) * 4 + 3) * 64 + lane];

        int pa = pkA[s], pb = pkB[s];                     // static index
        float4 wA = wtA[s], wB = wtB[s];

        int iA = pa & 0x3FFF, dA = (pa >> 14) & 1, fA = (pa >> 15) & 1;
        int iB = pb & 0x3FFF, dB = (pb >> 14) & 1, fB = (pb >> 15) & 1;
        int yc0A = iA >> 7, xc0A = iA & 127, xc1A = xc0A + dA, yc1A = yc0A + fA;
        int yc0B = iB >> 7, xc0B = iB & 127, xc1B = xc0B + dB, yc1B = yc0B + fB;
        int ry0A = yc0A - row_lo, ry1A = ry0A + fA;
        int ry0B = yc0B - row_lo, ry1B = ry0B + fB;
        int r0A = min(max(ry0A, 0), NROWS - 1), r1A = min(max(ry1A, 0), NROWS - 1);
        int r0B = min(max(ry0B, 0), NROWS - 1), r1B = min(max(ry1B, 0), NROWS - 1);

        ushort8 A0a = LRD(r0A, xc0A, khalf),     A0b = LRD(r0A, xc0A, khalf + 4);
        ushort8 A1a = LRD(r0A, xc1A, khalf),     A1b = LRD(r0A, xc1A, khalf + 4);
        ushort8 A2a = LRD(r1A, xc0A, khalf),     A2b = LRD(r1A, xc0A, khalf + 4);
        ushort8 A3a = LRD(r1A, xc1A, khalf),     A3b = LRD(r1A, xc1A, khalf + 4);
        ushort8 B0a = LRD(r0B, xc0B, khalf),     B0b = LRD(r0B, xc0B, khalf + 4);
        ushort8 B1a = LRD(r0B, xc1B, khalf),     B1b = LRD(r0B, xc1B, khalf + 4);
        ushort8 B2a = LRD(r1B, xc0B, khalf),     B2b = LRD(r1B, xc0B, khalf + 4);
        ushort8 B3a = LRD(r1B, xc1B, khalf),     B3b = LRD(r1B, xc1B, khalf + 4);

        if ((unsigned)ry0A >= (unsigned)NROWS) {
            A0a = GRD(yc0A * WW + xc0A, 0);  A0b = GRD(yc0A * WW + xc0A, 1);
            A1a = GRD(yc0A * WW + xc1A, 0);  A1b = GRD(yc0A * WW + xc1A, 1);
        }
        if ((unsigned)ry1A >= (unsigned)NROWS) {
            A2a = GRD(yc1A * WW + xc0A, 0);  A2b = GRD(yc1A * WW + xc0A, 1);
            A3a = GRD(yc1A * WW + xc1A, 0);  A3b = GRD(yc1A * WW + xc1A, 1);
        }
        if ((unsigned)ry0B >= (unsigned)NROWS) {
            B0a = GRD(yc0B * WW + xc0B, 0);  B0b = GRD(yc0B * WW + xc0B, 1);
            B1a = GRD(yc0B * WW + xc1B, 0);  B1b = GRD(yc0B * WW + xc1B, 1);
        }
        if ((unsigned)ry1B >= (unsigned)NROWS) {
            B2a = GRD(yc1B * WW + xc0B, 0);  B2b = GRD(yc1B * WW + xc0B, 1);
            B3a = GRD(yc1B * WW + xc1B, 0);  B3b = GRD(yc1B * WW + xc1B, 1);
        }

        short8 aA0, aA1, aB0, aB1;
        #pragma unroll
        for (int j = 0; j < 8; ++j) {
            float v0 = wA.x * bf2f(A0a[j]) + wA.y * bf2f(A1a[j])
                     + wA.z * bf2f(A2a[j]) + wA.w * bf2f(A3a[j]);
            float v1 = wA.x * bf2f(A0b[j]) + wA.y * bf2f(A1b[j])
                     + wA.z * bf2f(A2b[j]) + wA.w * bf2f(A3b[j]);
            float u0 = wB.x * bf2f(B0a[j]) + wB.y * bf2f(B1a[j])
                     + wB.z * bf2f(B2a[j]) + wB.w * bf2f(B3a[j]);
            float u1 = wB.x * bf2f(B0b[j]) + wB.y * bf2f(B1b[j])
                     + wB.z * bf2f(B2b[j]) + wB.w * bf2f(B3b[j]);
            aA0[j] = f2bf(v0);  aA1[j] = f2bf(v1);
            aB0[j] = f2bf(u0);  aB1[j] = f2bf(u1);
        }
        accA0 = __builtin_amdgcn_mfma_f32_16x16x32_bf16(aA0, b00, accA0, 0, 0, 0);
        accA1 = __builtin_amdgcn_mfma_f32_16x16x32_bf16(aA0, b01, accA1, 0, 0, 0);
        accA2 = __builtin_amdgcn_mfma_f32_16x16x32_bf16(aA0, b02, accA2, 0, 0, 0);
        accA3 = __builtin_amdgcn_mfma_f32_16x16x32_bf16(aA0, b03, accA3, 0, 0, 0);
        accB0 = __builtin_amdgcn_mfma_f32_16x16x32_bf16(aB0, b00, accB0, 0, 0, 0);
        accB1 = __builtin_amdgcn_mfma_f32_16x16x32_bf16(aB0, b01, accB1, 0, 0, 0);
        accB2 = __builtin_amdgcn_mfma_f32_16x16x32_bf16(aB0, b02, accB2, 0, 0, 0);
        accB3 = __builtin_amdgcn_mfma_f32_16x16x32_bf16(aB0, b03, accB3, 0, 0, 0);
        accA0 = __builtin_amdgcn_mfma_f32_16x16x32_bf16(aA1, b10, accA0, 0, 0, 0);
        accA1 = __builtin_amdgcn_mfma_f32_16x16x32_bf16(aA1, b11, accA1, 0, 0, 0);
        accA2 = __builtin_amdgcn_mfma_f32_16x16x32_bf16(aA1, b12, accA2, 0, 0, 0);
        accA3 = __builtin_amdgcn_mfma_f32_16x16x32_bf16(aA1, b13, accA3, 0, 0, 0);
        accB0 = __builtin_amdgcn_mfma_f32_16x16x32_bf16(aB1, b10, accB0, 0, 0, 0);
        accB1 = __builtin_amdgcn_mfma_f32_16x16x32_bf16(aB1, b11, accB1, 0, 0, 0);
        accB2 = __builtin_amdgcn_mfma_f32_16x16x32_bf16(aB1, b12, accB2, 0, 0, 0);
        accB3 = __builtin_amdgcn_mfma_f32_16x16x32_bf16(aB1, b13, accB3, 0, 0, 0);
    }

    // ---- epilogue: NONTEMPORAL f32x4 stores (lane holds 4 consecutive pixels per o) ----
    {
        int ocol = lane & 15;
        int pixA = wl * 32 + khalf * 4;
        float* ob = out + ((size_t)b * COUT) * HW + ho * WW;
        f32x4* dst;
        dst = (f32x4*)(ob + (size_t)(0 * 16 + ocol) * HW + pixA);
        __builtin_nontemporal_store(accA0, dst);
        __builtin_nontemporal_store(accB0, dst + 4);
        dst = (f32x4*)(ob + (size_t)(1 * 16 + ocol) * HW + pixA);
        __builtin_nontemporal_store(accA1, dst);
        __builtin_nontemporal_store(accB1, dst + 4);
        dst = (f32x4*)(ob + (size_t)(2 * 16 + ocol) * HW + pixA);
        __builtin_nontemporal_store(accA2, dst);
        __builtin_nontemporal_store(accB2, dst + 4);
        dst = (f32x4*)(ob + (size_t)(3 * 16 + ocol) * HW + pixA);
        __builtin_nontemporal_store(accA3, dst);
        __builtin_nontemporal_store(accB3, dst + 4);
    }
}

extern "C" void kernel_launch(void* const* d_in, const int* in_sizes, int n_in,
                              void* d_out, int out_size, void* d_ws, size_t ws_size,
                              hipStream_t stream)
{
    const float* x    = (const float*)d_in[0];
    const float* woff = (const float*)d_in[1];
    const float* wdef = (const float*)d_in[2];
    float* out  = (float*)d_out;

    unsigned short* wfrag = (unsigned short*)d_ws;          // 73.7 KB
    unsigned short* wfo   = wfrag + 36864;                  // 36.9 KB
    unsigned short* xT    = wfo + 18432;                    // 16.8 MB

    hipLaunchKernelGGL(to_chlast_k, dim3(BATCH * HH), dim3(256), 0, stream,
                       x, xT);
    hipLaunchKernelGGL(build_wfrag_k, dim3(COUT * 576 / 256), dim3(256), 0, stream,
                       wdef, wfrag);
    hipLaunchKernelGGL(build_wfo_k, dim3(32 * 576 / 256), dim3(256), 0, stream,
                       woff, wfo);
    hipLaunchKernelGGL(deform_fused6_k, dim3((HH / 2) * 8), dim3(512), 0, stream,
                       xT, (const short8*)wfo, (const short8*)wfrag, out);
}

// Round 15
// 59.300 us; speedup vs baseline: 1.1691x; 1.1691x over previous
//
#include <hip/hip_runtime.h>
#include <hip/hip_bf16.h>

#define BATCH 8
#define CIN   64
#define COUT  64
#define HH    128
#define WW    128
#define HW    (HH * WW)
#define OFFC  18
#define KK    9
#define NROWS 7
#define ROWB  (WW * 128)          // 16384 B per staged row (128 px x 128 B)

typedef __attribute__((ext_vector_type(8))) _Float16 half8;
typedef __attribute__((ext_vector_type(8))) unsigned short ushort8;
typedef __attribute__((ext_vector_type(4))) float f32x4;

__device__ __forceinline__ unsigned short f2hbits(float v) {
    _Float16 h = (_Float16)v;
    return __builtin_bit_cast(unsigned short, h);
}
__device__ __forceinline__ half8 splat8(float f) {
    _Float16 h = (_Float16)f;
    return (half8){h, h, h, h, h, h, h, h};
}

// ------- Kernel X: x (b,c,h,w) f32 -> xT (b,h,w,c) f16 -------
__global__ __launch_bounds__(256) void to_chlast_k(
    const float* __restrict__ x, unsigned short* __restrict__ xT)
{
    __shared__ unsigned short t[128 * 72];
    int blk = blockIdx.x;                    // ho*8 + b
    int b  = blk & 7;
    int ho = blk >> 3;
    int tid = threadIdx.x;

    const float* xr = x + (size_t)b * CIN * HW + ho * WW;
    for (int i = tid; i < 2048; i += 256) {
        int c = i >> 5, w4 = (i & 31) * 4;
        float4 v = *(const float4*)(xr + (size_t)c * HW + w4);
        t[(w4 + 0) * 72 + c] = f2hbits(v.x);
        t[(w4 + 1) * 72 + c] = f2hbits(v.y);
        t[(w4 + 2) * 72 + c] = f2hbits(v.z);
        t[(w4 + 3) * 72 + c] = f2hbits(v.w);
    }
    __syncthreads();

    unsigned short* orow = xT + (size_t)(b * HH + ho) * WW * 64;
    for (int j = tid; j < 1024; j += 256) {
        int w = j >> 3, c8 = (j & 7) * 8;
        *(ushort8*)(orow + w * 64 + c8) = *(const ushort8*)(t + w * 72 + c8);
    }
}

// ------- Kernel B: w_deform -> f16 B-fragments wf[kk][nt(4)][lane][8] -------
__global__ __launch_bounds__(256) void build_wfrag_k(
    const float* __restrict__ wd, unsigned short* __restrict__ wf)
{
    int idx = blockIdx.x * 256 + threadIdx.x;
    int ck = idx % 576;
    int o  = idx / 576;
    int c = ck & 63, k = ck >> 6;
    float v = wd[o * 576 + c * 9 + k];
    int kk = ck >> 5, nt = o >> 4;
    int lane = (o & 15) | (((ck >> 3) & 3) << 4);
    int j = ck & 7;
    wf[((kk * 4 + nt) * 64 + lane) * 8 + j] = f2hbits(v);
}

// ------- Kernel B2: w_offset -> f16 B-fragments wfo[kk][nt(2)][lane][8], N pad 18->32 -------
__global__ __launch_bounds__(256) void build_wfo_k(
    const float* __restrict__ wo, unsigned short* __restrict__ wfo)
{
    int idx = blockIdx.x * 256 + threadIdx.x;
    if (idx >= 32 * 576) return;
    int ck = idx % 576;
    int ov = idx / 576;
    int c = ck & 63, tap = ck >> 6;
    float v = (ov < OFFC) ? wo[ov * 576 + c * 9 + tap] : 0.f;
    int kk = ck >> 5, nt = ov >> 4;
    int lane = (ov & 15) | (((ck >> 3) & 3) << 4);
    int j = ck & 7;
    wfo[((kk * 2 + nt) * 64 + lane) * 8 + j] = f2hbits(v);
}

// ---------------- Kernel C: LDS-staged gather, 2-row/512-thr, PACKED-F16 interp ----------------
// R13 structure (inline positions, no rotation) with the whole datapath in f16:
// interp = half8 packed ops (v_pk_fma_f16, 4 ops per 2 channels) -> ~64 VALU/tap vs
// ~290 for the f32/bf16 path, and ZERO format conversions (result IS the MFMA frag).
// f16 has 10-bit mantissa vs bf16's 7 -> accuracy improves. MFMA: f32_16x16x32_f16.
__global__ __launch_bounds__(512, 1) void deform_fused7_k(
    const unsigned short* __restrict__ xT,
    const half8* __restrict__ wfo,
    const half8* __restrict__ wf, float* __restrict__ out)
{
    __shared__ char  stage[NROWS * ROWB];   // 114688 B
    __shared__ float offsL[8][32 * 20];     // 20480 B  (total 135168 B)

    int tid  = threadIdx.x;
    int blk  = blockIdx.x;                  // rowpair*8 + b
    int b    = blk & 7;
    int ho0  = (blk >> 3) * 2;
    int row_lo = ho0 - 2;                   // staged rows row_lo .. row_lo+6

    const unsigned short* pT = xT + (size_t)b * HW * 64;

    int lane  = tid & 63;
    int wave  = tid >> 6;                   // 0..7
    int wl    = wave & 3;
    int ho    = ho0 + (wave >> 2);
    int prow  = lane & 15;
    int khalf = lane >> 4;
    int px0   = wl * 32 + prow;
    int px1   = px0 + 16;

    // ---- STAGE: rows row_lo..row_lo+6 of xT[b] -> swizzled LDS (512 threads) ----
    for (int c = tid; c < NROWS * 1024; c += 512) {
        int r  = c >> 10;
        int ar = row_lo + r;
        if ((unsigned)ar < (unsigned)HH) {
            int px   = (c >> 3) & 127;
            int slot = c & 7;
            ushort8 v = *(const ushort8*)(pT + (((size_t)ar * WW + px) << 6) + slot * 8);
            *(ushort8*)(stage + r * ROWB + px * 128 + ((slot ^ (px & 7)) << 4)) = v;
        }
    }
    __syncthreads();

    auto LRD = [&](int r, int xc, int slot) -> half8 {
        return *(const half8*)(stage + r * ROWB + xc * 128 + ((slot ^ (xc & 7)) << 4));
    };
    auto GRD = [&](int idx, int h) -> half8 {
        return *(const half8*)(pT + ((size_t)idx << 6) + (khalf << 3) + h * 32);
    };

    // ---- phase A: offsets conv via MFMA (f16) from the stage ----
    {
        f32x4 oa00 = {0.f,0.f,0.f,0.f}, oa01 = {0.f,0.f,0.f,0.f};
        f32x4 oa10 = {0.f,0.f,0.f,0.f}, oa11 = {0.f,0.f,0.f,0.f};
        #pragma unroll
        for (int kk = 0; kk < 18; ++kk) {
            int tap = kk >> 1;
            int y   = ho + tap / 3 - 1;
            int dx  = tap % 3 - 1;
            int slot = khalf + (kk & 1) * 4;
            half8 a0 = {0,0,0,0,0,0,0,0};
            half8 a1 = {0,0,0,0,0,0,0,0};
            int xw0 = px0 + dx, xw1 = px1 + dx;
            if ((unsigned)y < HH) {
                int ry = y - row_lo;        // in [1,4], always staged
                if ((unsigned)xw0 < WW) a0 = LRD(ry, xw0, slot);
                if ((unsigned)xw1 < WW) a1 = LRD(ry, xw1, slot);
            }
            half8 b0 = wfo[(kk * 2 + 0) * 64 + lane];
            half8 b1 = wfo[(kk * 2 + 1) * 64 + lane];
            oa00 = __builtin_amdgcn_mfma_f32_16x16x32_f16(a0, b0, oa00, 0, 0, 0);
            oa01 = __builtin_amdgcn_mfma_f32_16x16x32_f16(a0, b1, oa01, 0, 0, 0);
            oa10 = __builtin_amdgcn_mfma_f32_16x16x32_f16(a1, b0, oa10, 0, 0, 0);
            oa11 = __builtin_amdgcn_mfma_f32_16x16x32_f16(a1, b1, oa11, 0, 0, 0);
        }
        int ocol = lane & 15;
        int pl0  = khalf * 4;
        #pragma unroll
        for (int r = 0; r < 4; ++r) {
            offsL[wave][(pl0 + r) * 20 + ocol]      = oa00[r];
            offsL[wave][(pl0 + 16 + r) * 20 + ocol] = oa10[r];
        }
        if (ocol < 2) {
            #pragma unroll
            for (int r = 0; r < 4; ++r) {
                offsL[wave][(pl0 + r) * 20 + 16 + ocol]      = oa01[r];
                offsL[wave][(pl0 + 16 + r) * 20 + 16 + ocol] = oa11[r];
            }
        }
    }
    // no barrier: offsL slice is wave-private

    // ---- tap loop: inline positions + LDS gather + packed-f16 interp + MFMA ----
    f32x4 accA0 = {0.f,0.f,0.f,0.f}, accA1 = {0.f,0.f,0.f,0.f};
    f32x4 accA2 = {0.f,0.f,0.f,0.f}, accA3 = {0.f,0.f,0.f,0.f};
    f32x4 accB0 = {0.f,0.f,0.f,0.f}, accB1 = {0.f,0.f,0.f,0.f};
    f32x4 accB2 = {0.f,0.f,0.f,0.f}, accB3 = {0.f,0.f,0.f,0.f};

    #pragma unroll
    for (int t = 0; t < 9; ++t) {
        half8 b00 = wf[((2 * t) * 4 + 0) * 64 + lane];
        half8 b01 = wf[((2 * t) * 4 + 1) * 64 + lane];
        half8 b02 = wf[((2 * t) * 4 + 2) * 64 + lane];
        half8 b03 = wf[((2 * t) * 4 + 3) * 64 + lane];
        half8 b10 = wf[((2 * t + 1) * 4 + 0) * 64 + lane];
        half8 b11 = wf[((2 * t + 1) * 4 + 1) * 64 + lane];
        half8 b12 = wf[((2 * t + 1) * 4 + 2) * 64 + lane];
        half8 b13 = wf[((2 * t + 1) * 4 + 3) * 64 + lane];

        // ---------- tile A positions ----------
        float dyA = offsL[wave][prow * 20 + 2 * t];
        float dxA = offsL[wave][prow * 20 + 2 * t + 1];
        float yyA = (float)(ho - 1 + t / 3) + dyA;
        float xxA = (float)(px0 - 1 + t % 3) + dxA;
        float y0A = floorf(yyA), x0A = floorf(xxA);
        float wy1A = yyA - y0A, wx1A = xxA - x0A;
        float wy0A = 1.f - wy1A, wx0A = 1.f - wx1A;
        bool vA = (yyA > -1.f) && (yyA < (float)HH) && (xxA > -1.f) && (xxA < (float)WW);
        int y0iA = (int)y0A, x0iA = (int)x0A;
        bool iy0A = (unsigned)y0iA < HH, iy1A = (unsigned)(y0iA + 1) < HH;
        bool ix0A = (unsigned)x0iA < WW, ix1A = (unsigned)(x0iA + 1) < WW;
        float wA00 = wy0A * wx0A * ((vA && iy0A && ix0A) ? 1.f : 0.f);
        float wA01 = wy0A * wx1A * ((vA && iy0A && ix1A) ? 1.f : 0.f);
        float wA10 = wy1A * wx0A * ((vA && iy1A && ix0A) ? 1.f : 0.f);
        float wA11 = wy1A * wx1A * ((vA && iy1A && ix1A) ? 1.f : 0.f);
        int yc0A = min(max(y0iA, 0), HH - 1), yc1A = min(max(y0iA + 1, 0), HH - 1);
        int xc0A = min(max(x0iA, 0), WW - 1), xc1A = min(max(x0iA + 1, 0), WW - 1);

        // ---------- tile B positions ----------
        float dyB = offsL[wave][(prow + 16) * 20 + 2 * t];
        float dxB = offsL[wave][(prow + 16) * 20 + 2 * t + 1];
        float yyB = (float)(ho - 1 + t / 3) + dyB;
        float xxB = (float)(px1 - 1 + t % 3) + dxB;
        float y0B = floorf(yyB), x0B = floorf(xxB);
        float wy1B = yyB - y0B, wx1B = xxB - x0B;
        float wy0B = 1.f - wy1B, wx0B = 1.f - wx1B;
        bool vB = (yyB > -1.f) && (yyB < (float)HH) && (xxB > -1.f) && (xxB < (float)WW);
        int y0iB = (int)y0B, x0iB = (int)x0B;
        bool iy0B = (unsigned)y0iB < HH, iy1B = (unsigned)(y0iB + 1) < HH;
        bool ix0B = (unsigned)x0iB < WW, ix1B = (unsigned)(x0iB + 1) < WW;
        float wB00 = wy0B * wx0B * ((vB && iy0B && ix0B) ? 1.f : 0.f);
        float wB01 = wy0B * wx1B * ((vB && iy0B && ix1B) ? 1.f : 0.f);
        float wB10 = wy1B * wx0B * ((vB && iy1B && ix0B) ? 1.f : 0.f);
        float wB11 = wy1B * wx1B * ((vB && iy1B && ix1B) ? 1.f : 0.f);
        int yc0B = min(max(y0iB, 0), HH - 1), yc1B = min(max(y0iB + 1, 0), HH - 1);
        int xc0B = min(max(x0iB, 0), WW - 1), xc1B = min(max(x0iB + 1, 0), WW - 1);

        // ---------- LDS gathers (ds_read_b128), clamped row index ----------
        int ry0A = yc0A - row_lo, ry1A = yc1A - row_lo;
        int ry0B = yc0B - row_lo, ry1B = yc1B - row_lo;
        int r0A = min(max(ry0A, 0), NROWS - 1), r1A = min(max(ry1A, 0), NROWS - 1);
        int r0B = min(max(ry0B, 0), NROWS - 1), r1B = min(max(ry1B, 0), NROWS - 1);

        half8 A0a = LRD(r0A, xc0A, khalf),     A0b = LRD(r0A, xc0A, khalf + 4);
        half8 A1a = LRD(r0A, xc1A, khalf),     A1b = LRD(r0A, xc1A, khalf + 4);
        half8 A2a = LRD(r1A, xc0A, khalf),     A2b = LRD(r1A, xc0A, khalf + 4);
        half8 A3a = LRD(r1A, xc1A, khalf),     A3b = LRD(r1A, xc1A, khalf + 4);
        half8 B0a = LRD(r0B, xc0B, khalf),     B0b = LRD(r0B, xc0B, khalf + 4);
        half8 B1a = LRD(r0B, xc1B, khalf),     B1b = LRD(r0B, xc1B, khalf + 4);
        half8 B2a = LRD(r1B, xc0B, khalf),     B2b = LRD(r1B, xc0B, khalf + 4);
        half8 B3a = LRD(r1B, xc1B, khalf),     B3b = LRD(r1B, xc1B, khalf + 4);

        // ---------- rare out-of-tile fallbacks (same bytes from global) ----------
        if ((unsigned)ry0A >= (unsigned)NROWS) {
            A0a = GRD(yc0A * WW + xc0A, 0);  A0b = GRD(yc0A * WW + xc0A, 1);
            A1a = GRD(yc0A * WW + xc1A, 0);  A1b = GRD(yc0A * WW + xc1A, 1);
        }
        if ((unsigned)ry1A >= (unsigned)NROWS) {
            A2a = GRD(yc1A * WW + xc0A, 0);  A2b = GRD(yc1A * WW + xc0A, 1);
            A3a = GRD(yc1A * WW + xc1A, 0);  A3b = GRD(yc1A * WW + xc1A, 1);
        }
        if ((unsigned)ry0B >= (unsigned)NROWS) {
            B0a = GRD(yc0B * WW + xc0B, 0);  B0b = GRD(yc0B * WW + xc0B, 1);
            B1a = GRD(yc0B * WW + xc1B, 0);  B1b = GRD(yc0B * WW + xc1B, 1);
        }
        if ((unsigned)ry1B >= (unsigned)NROWS) {
            B2a = GRD(yc1B * WW + xc0B, 0);  B2b = GRD(yc1B * WW + xc0B, 1);
            B3a = GRD(yc1B * WW + xc1B, 0);  B3b = GRD(yc1B * WW + xc1B, 1);
        }

        // ---------- packed-f16 interp: result IS the MFMA fragment ----------
        half8 sA00 = splat8(wA00), sA01 = splat8(wA01), sA10 = splat8(wA10), sA11 = splat8(wA11);
        half8 sB00 = splat8(wB00), sB01 = splat8(wB01), sB10 = splat8(wB10), sB11 = splat8(wB11);
        half8 aA0 = A0a * sA00 + A1a * sA01 + A2a * sA10 + A3a * sA11;
        half8 aA1 = A0b * sA00 + A1b * sA01 + A2b * sA10 + A3b * sA11;
        half8 aB0 = B0a * sB00 + B1a * sB01 + B2a * sB10 + B3a * sB11;
        half8 aB1 = B0b * sB00 + B1b * sB01 + B2b * sB10 + B3b * sB11;

        accA0 = __builtin_amdgcn_mfma_f32_16x16x32_f16(aA0, b00, accA0, 0, 0, 0);
        accA1 = __builtin_amdgcn_mfma_f32_16x16x32_f16(aA0, b01, accA1, 0, 0, 0);
        accA2 = __builtin_amdgcn_mfma_f32_16x16x32_f16(aA0, b02, accA2, 0, 0, 0);
        accA3 = __builtin_amdgcn_mfma_f32_16x16x32_f16(aA0, b03, accA3, 0, 0, 0);
        accB0 = __builtin_amdgcn_mfma_f32_16x16x32_f16(aB0, b00, accB0, 0, 0, 0);
        accB1 = __builtin_amdgcn_mfma_f32_16x16x32_f16(aB0, b01, accB1, 0, 0, 0);
        accB2 = __builtin_amdgcn_mfma_f32_16x16x32_f16(aB0, b02, accB2, 0, 0, 0);
        accB3 = __builtin_amdgcn_mfma_f32_16x16x32_f16(aB0, b03, accB3, 0, 0, 0);
        accA0 = __builtin_amdgcn_mfma_f32_16x16x32_f16(aA1, b10, accA0, 0, 0, 0);
        accA1 = __builtin_amdgcn_mfma_f32_16x16x32_f16(aA1, b11, accA1, 0, 0, 0);
        accA2 = __builtin_amdgcn_mfma_f32_16x16x32_f16(aA1, b12, accA2, 0, 0, 0);
        accA3 = __builtin_amdgcn_mfma_f32_16x16x32_f16(aA1, b13, accA3, 0, 0, 0);
        accB0 = __builtin_amdgcn_mfma_f32_16x16x32_f16(aB1, b10, accB0, 0, 0, 0);
        accB1 = __builtin_amdgcn_mfma_f32_16x16x32_f16(aB1, b11, accB1, 0, 0, 0);
        accB2 = __builtin_amdgcn_mfma_f32_16x16x32_f16(aB1, b12, accB2, 0, 0, 0);
        accB3 = __builtin_amdgcn_mfma_f32_16x16x32_f16(aB1, b13, accB3, 0, 0, 0);
    }

    // ---- epilogue: NONTEMPORAL f32x4 stores (lane holds 4 consecutive pixels per o) ----
    {
        int ocol = lane & 15;
        int pixA = wl * 32 + khalf * 4;
        float* ob = out + ((size_t)b * COUT) * HW + ho * WW;
        f32x4* dst;
        dst = (f32x4*)(ob + (size_t)(0 * 16 + ocol) * HW + pixA);
        __builtin_nontemporal_store(accA0, dst);
        __builtin_nontemporal_store(accB0, dst + 4);
        dst = (f32x4*)(ob + (size_t)(1 * 16 + ocol) * HW + pixA);
        __builtin_nontemporal_store(accA1, dst);
        __builtin_nontemporal_store(accB1, dst + 4);
        dst = (f32x4*)(ob + (size_t)(2 * 16 + ocol) * HW + pixA);
        __builtin_nontemporal_store(accA2, dst);
        __builtin_nontemporal_store(accB2, dst + 4);
        dst = (f32x4*)(ob + (size_t)(3 * 16 + ocol) * HW + pixA);
        __builtin_nontemporal_store(accA3, dst);
        __builtin_nontemporal_store(accB3, dst + 4);
    }
}

extern "C" void kernel_launch(void* const* d_in, const int* in_sizes, int n_in,
                              void* d_out, int out_size, void* d_ws, size_t ws_size,
                              hipStream_t stream)
{
    const float* x    = (const float*)d_in[0];
    const float* woff = (const float*)d_in[1];
    const float* wdef = (const float*)d_in[2];
    float* out  = (float*)d_out;

    unsigned short* wfrag = (unsigned short*)d_ws;          // 73.7 KB
    unsigned short* wfo   = wfrag + 36864;                  // 36.9 KB
    unsigned short* xT    = wfo + 18432;                    // 16.8 MB

    hipLaunchKernelGGL(to_chlast_k, dim3(BATCH * HH), dim3(256), 0, stream,
                       x, xT);
    hipLaunchKernelGGL(build_wfrag_k, dim3(COUT * 576 / 256), dim3(256), 0, stream,
                       wdef, wfrag);
    hipLaunchKernelGGL(build_wfo_k, dim3(32 * 576 / 256), dim3(256), 0, stream,
                       woff, wfo);
    hipLaunchKernelGGL(deform_fused7_k, dim3((HH / 2) * 8), dim3(512), 0, stream,
                       xT, (const half8*)wfo, (const half8*)wfrag, out);
}

// Round 16
// 54.877 us; speedup vs baseline: 1.2633x; 1.0806x over previous
//
#include <hip/hip_runtime.h>
#include <hip/hip_bf16.h>

#define BATCH 8
#define CIN   64
#define COUT  64
#define HH    128
#define WW    128
#define HW    (HH * WW)
#define OFFC  18
#define KK    9
#define NROWS 7
#define SPX   68                  // staged columns: 64 + 2 halo each side
#define ROWB2 (SPX * 128)         // 8704 B per staged row

typedef __attribute__((ext_vector_type(8))) _Float16 half8;
typedef __attribute__((ext_vector_type(8))) unsigned short ushort8;
typedef __attribute__((ext_vector_type(4))) float f32x4;

__device__ __forceinline__ unsigned short f2hbits(float v) {
    _Float16 h = (_Float16)v;
    return __builtin_bit_cast(unsigned short, h);
}
__device__ __forceinline__ half8 splat8(float f) {
    _Float16 h = (_Float16)f;
    return (half8){h, h, h, h, h, h, h, h};
}

// ------- Kernel X: x (b,c,h,w) f32 -> xT (b,h,w,c) f16 -------
__global__ __launch_bounds__(256) void to_chlast_k(
    const float* __restrict__ x, unsigned short* __restrict__ xT)
{
    __shared__ unsigned short t[128 * 72];
    int blk = blockIdx.x;                    // ho*8 + b
    int b  = blk & 7;
    int ho = blk >> 3;
    int tid = threadIdx.x;

    const float* xr = x + (size_t)b * CIN * HW + ho * WW;
    for (int i = tid; i < 2048; i += 256) {
        int c = i >> 5, w4 = (i & 31) * 4;
        float4 v = *(const float4*)(xr + (size_t)c * HW + w4);
        t[(w4 + 0) * 72 + c] = f2hbits(v.x);
        t[(w4 + 1) * 72 + c] = f2hbits(v.y);
        t[(w4 + 2) * 72 + c] = f2hbits(v.z);
        t[(w4 + 3) * 72 + c] = f2hbits(v.w);
    }
    __syncthreads();

    unsigned short* orow = xT + (size_t)(b * HH + ho) * WW * 64;
    for (int j = tid; j < 1024; j += 256) {
        int w = j >> 3, c8 = (j & 7) * 8;
        *(ushort8*)(orow + w * 64 + c8) = *(const ushort8*)(t + w * 72 + c8);
    }
}

// ------- Kernel B (merged): w_deform -> wf frags; w_offset -> wfo frags (f16) -------
__global__ __launch_bounds__(256) void build_w_k(
    const float* __restrict__ wd, const float* __restrict__ wo,
    unsigned short* __restrict__ wf, unsigned short* __restrict__ wfo)
{
    int idx = blockIdx.x * 256 + threadIdx.x;
    if (idx < 36864) {                               // wf: o*576 + ck
        int ck = idx % 576;
        int o  = idx / 576;
        int c = ck & 63, k = ck >> 6;
        float v = wd[o * 576 + c * 9 + k];
        int kk = ck >> 5, nt = o >> 4;
        int lane = (o & 15) | (((ck >> 3) & 3) << 4);
        int j = ck & 7;
        wf[((kk * 4 + nt) * 64 + lane) * 8 + j] = f2hbits(v);
    } else if (idx < 36864 + 18432) {                // wfo: ov*576 + ck, N pad 18->32
        int i2 = idx - 36864;
        int ck = i2 % 576;
        int ov = i2 / 576;
        int c = ck & 63, tap = ck >> 6;
        float v = (ov < OFFC) ? wo[ov * 576 + c * 9 + tap] : 0.f;
        int kk = ck >> 5, nt = ov >> 4;
        int lane = (ov & 15) | (((ck >> 3) & 3) << 4);
        int j = ck & 7;
        wfo[((kk * 2 + nt) * 64 + lane) * 8 + j] = f2hbits(v);
    }
}

// ---------- Kernel C: LDS-staged gather, 2-row x 64-px / 512-thr, 2 blocks/CU ----------
// R15 was locked at 1 block/CU (112KB stage) = 2 waves/SIMD -> ds_read latency exposed.
// Now: block = 2 rows x 64 px; stage = 7 rows x 68 cols (+-2 col halo) = 60.9KB;
// + offsL 10KB = 71.2KB -> 2 blocks/CU -> 4 waves/SIMD (2x TLP). Each of 8 waves owns
// 16 px (1 A-tile, 8 MFMAs/tap). Out-of-stage rows OR cols -> exec-masked global
// fallback of the SAME xT bytes (bit-identical, rare). Packed-f16 interp (R15).
__global__ __launch_bounds__(512, 4) void deform_fused8_k(
    const unsigned short* __restrict__ xT,
    const half8* __restrict__ wfo,
    const half8* __restrict__ wf, float* __restrict__ out)
{
    __shared__ char  stage[NROWS * ROWB2];  // 60928 B
    __shared__ float offsL[8][16 * 20];     // 10240 B  (total 71168 B)

    int tid  = threadIdx.x;
    int blk  = blockIdx.x;                  // (rp*2+wseg)*8 + b
    int b    = blk & 7;
    int t2   = blk >> 3;
    int wseg = t2 & 1;
    int ho0  = (t2 >> 1) * 2;
    int row_lo = ho0 - 2;                   // staged rows row_lo .. row_lo+6
    int wo0  = wseg * 64;
    int col_lo = wo0 - 2;                   // staged cols col_lo .. col_lo+67

    const unsigned short* pT = xT + (size_t)b * HW * 64;

    int lane  = tid & 63;
    int wave  = tid >> 6;                   // 0..7
    int wl    = wave & 3;                   // px quarter
    int ho    = ho0 + (wave >> 2);          // this wave's output row
    int prow  = lane & 15;
    int khalf = lane >> 4;
    int px    = wo0 + wl * 16 + prow;       // this lane's pixel (absolute)

    // ---- STAGE: 7 rows x 68 cols of xT[b] -> swizzled LDS ----
    for (int c = tid; c < NROWS * SPX * 8; c += 512) {
        int r    = c / (SPX * 8);
        int rem  = c - r * (SPX * 8);
        int xs   = rem >> 3;
        int slot = rem & 7;
        int ar = row_lo + r, ac = col_lo + xs;
        if ((unsigned)ar < (unsigned)HH && (unsigned)ac < (unsigned)WW) {
            ushort8 v = *(const ushort8*)(pT + (((size_t)ar * WW + ac) << 6) + slot * 8);
            *(ushort8*)(stage + r * ROWB2 + xs * 128 + ((slot ^ (xs & 7)) << 4)) = v;
        }
    }
    __syncthreads();

    auto LRD = [&](int r, int xs, int slot) -> half8 {
        return *(const half8*)(stage + r * ROWB2 + xs * 128 + ((slot ^ (xs & 7)) << 4));
    };
    auto GRD = [&](int idx, int h) -> half8 {
        return *(const half8*)(pT + ((size_t)idx << 6) + (khalf << 3) + h * 32);
    };

    // ---- phase A: offsets conv via MFMA (f16) from the stage ----
    {
        f32x4 oa0 = {0.f,0.f,0.f,0.f}, oa1 = {0.f,0.f,0.f,0.f};
        #pragma unroll
        for (int kk = 0; kk < 18; ++kk) {
            int tap = kk >> 1;
            int y   = ho + tap / 3 - 1;
            int dx  = tap % 3 - 1;
            int slot = khalf + (kk & 1) * 4;
            half8 a0 = {0,0,0,0,0,0,0,0};
            int xw = px + dx;
            if ((unsigned)y < HH && (unsigned)xw < WW) {
                a0 = LRD(y - row_lo, xw - col_lo, slot);   // ry in [1,4], xs in [1,66]
            }
            half8 b0 = wfo[(kk * 2 + 0) * 64 + lane];
            half8 b1 = wfo[(kk * 2 + 1) * 64 + lane];
            oa0 = __builtin_amdgcn_mfma_f32_16x16x32_f16(a0, b0, oa0, 0, 0, 0);
            oa1 = __builtin_amdgcn_mfma_f32_16x16x32_f16(a0, b1, oa1, 0, 0, 0);
        }
        int ocol = lane & 15;
        int pl0  = khalf * 4;
        #pragma unroll
        for (int r = 0; r < 4; ++r)
            offsL[wave][(pl0 + r) * 20 + ocol] = oa0[r];
        if (ocol < 2) {
            #pragma unroll
            for (int r = 0; r < 4; ++r)
                offsL[wave][(pl0 + r) * 20 + 16 + ocol] = oa1[r];
        }
    }
    // no barrier: offsL slice is wave-private

    // ---- tap loop: inline positions + LDS gather + packed-f16 interp + MFMA ----
    f32x4 acc0 = {0.f,0.f,0.f,0.f}, acc1 = {0.f,0.f,0.f,0.f};
    f32x4 acc2 = {0.f,0.f,0.f,0.f}, acc3 = {0.f,0.f,0.f,0.f};

    #pragma unroll
    for (int t = 0; t < 9; ++t) {
        half8 b00 = wf[((2 * t) * 4 + 0) * 64 + lane];
        half8 b01 = wf[((2 * t) * 4 + 1) * 64 + lane];
        half8 b02 = wf[((2 * t) * 4 + 2) * 64 + lane];
        half8 b03 = wf[((2 * t) * 4 + 3) * 64 + lane];
        half8 b10 = wf[((2 * t + 1) * 4 + 0) * 64 + lane];
        half8 b11 = wf[((2 * t + 1) * 4 + 1) * 64 + lane];
        half8 b12 = wf[((2 * t + 1) * 4 + 2) * 64 + lane];
        half8 b13 = wf[((2 * t + 1) * 4 + 3) * 64 + lane];

        // ---------- positions ----------
        float dy = offsL[wave][prow * 20 + 2 * t];
        float dx = offsL[wave][prow * 20 + 2 * t + 1];
        float yy = (float)(ho - 1 + t / 3) + dy;
        float xx = (float)(px - 1 + t % 3) + dx;
        float y0 = floorf(yy), x0 = floorf(xx);
        float wy1 = yy - y0, wx1 = xx - x0;
        float wy0 = 1.f - wy1, wx0 = 1.f - wx1;
        bool vv = (yy > -1.f) && (yy < (float)HH) && (xx > -1.f) && (xx < (float)WW);
        int y0i = (int)y0, x0i = (int)x0;
        bool iy0 = (unsigned)y0i < HH, iy1 = (unsigned)(y0i + 1) < HH;
        bool ix0 = (unsigned)x0i < WW, ix1 = (unsigned)(x0i + 1) < WW;
        float w00 = wy0 * wx0 * ((vv && iy0 && ix0) ? 1.f : 0.f);
        float w01 = wy0 * wx1 * ((vv && iy0 && ix1) ? 1.f : 0.f);
        float w10 = wy1 * wx0 * ((vv && iy1 && ix0) ? 1.f : 0.f);
        float w11 = wy1 * wx1 * ((vv && iy1 && ix1) ? 1.f : 0.f);
        int yc0 = min(max(y0i, 0), HH - 1), yc1 = min(max(y0i + 1, 0), HH - 1);
        int xc0 = min(max(x0i, 0), WW - 1), xc1 = min(max(x0i + 1, 0), WW - 1);

        // ---------- stage coords + in-stage tests ----------
        int ry0 = yc0 - row_lo, ry1 = yc1 - row_lo;
        int xs0 = xc0 - col_lo, xs1 = xc1 - col_lo;
        int r0 = min(max(ry0, 0), NROWS - 1), r1 = min(max(ry1, 0), NROWS - 1);
        int s0 = min(max(xs0, 0), SPX - 1),   s1 = min(max(xs1, 0), SPX - 1);
        bool colOOT = ((unsigned)xs0 >= (unsigned)SPX) || ((unsigned)xs1 >= (unsigned)SPX);
        bool bad0 = ((unsigned)ry0 >= (unsigned)NROWS) || colOOT;
        bool bad1 = ((unsigned)ry1 >= (unsigned)NROWS) || colOOT;

        // ---------- LDS gathers (ds_read_b128) ----------
        half8 C0a = LRD(r0, s0, khalf),     C0b = LRD(r0, s0, khalf + 4);
        half8 C1a = LRD(r0, s1, khalf),     C1b = LRD(r0, s1, khalf + 4);
        half8 C2a = LRD(r1, s0, khalf),     C2b = LRD(r1, s0, khalf + 4);
        half8 C3a = LRD(r1, s1, khalf),     C3b = LRD(r1, s1, khalf + 4);

        // ---------- rare out-of-stage fallbacks (same bytes from global) ----------
        if (bad0) {
            C0a = GRD(yc0 * WW + xc0, 0);  C0b = GRD(yc0 * WW + xc0, 1);
            C1a = GRD(yc0 * WW + xc1, 0);  C1b = GRD(yc0 * WW + xc1, 1);
        }
        if (bad1) {
            C2a = GRD(yc1 * WW + xc0, 0);  C2b = GRD(yc1 * WW + xc0, 1);
            C3a = GRD(yc1 * WW + xc1, 0);  C3b = GRD(yc1 * WW + xc1, 1);
        }

        // ---------- packed-f16 interp: result IS the MFMA fragment ----------
        half8 s00 = splat8(w00), s01 = splat8(w01), s10 = splat8(w10), s11 = splat8(w11);
        half8 a0 = C0a * s00 + C1a * s01 + C2a * s10 + C3a * s11;
        half8 a1 = C0b * s00 + C1b * s01 + C2b * s10 + C3b * s11;

        acc0 = __builtin_amdgcn_mfma_f32_16x16x32_f16(a0, b00, acc0, 0, 0, 0);
        acc1 = __builtin_amdgcn_mfma_f32_16x16x32_f16(a0, b01, acc1, 0, 0, 0);
        acc2 = __builtin_amdgcn_mfma_f32_16x16x32_f16(a0, b02, acc2, 0, 0, 0);
        acc3 = __builtin_amdgcn_mfma_f32_16x16x32_f16(a0, b03, acc3, 0, 0, 0);
        acc0 = __builtin_amdgcn_mfma_f32_16x16x32_f16(a1, b10, acc0, 0, 0, 0);
        acc1 = __builtin_amdgcn_mfma_f32_16x16x32_f16(a1, b11, acc1, 0, 0, 0);
        acc2 = __builtin_amdgcn_mfma_f32_16x16x32_f16(a1, b12, acc2, 0, 0, 0);
        acc3 = __builtin_amdgcn_mfma_f32_16x16x32_f16(a1, b13, acc3, 0, 0, 0);
    }

    // ---- epilogue: NONTEMPORAL f32x4 stores (lane holds 4 consecutive pixels per o) ----
    {
        int ocol = lane & 15;
        int pixA = wo0 + wl * 16 + khalf * 4;
        float* ob = out + ((size_t)b * COUT) * HW + ho * WW;
        __builtin_nontemporal_store(acc0, (f32x4*)(ob + (size_t)(0 * 16 + ocol) * HW + pixA));
        __builtin_nontemporal_store(acc1, (f32x4*)(ob + (size_t)(1 * 16 + ocol) * HW + pixA));
        __builtin_nontemporal_store(acc2, (f32x4*)(ob + (size_t)(2 * 16 + ocol) * HW + pixA));
        __builtin_nontemporal_store(acc3, (f32x4*)(ob + (size_t)(3 * 16 + ocol) * HW + pixA));
    }
}

extern "C" void kernel_launch(void* const* d_in, const int* in_sizes, int n_in,
                              void* d_out, int out_size, void* d_ws, size_t ws_size,
                              hipStream_t stream)
{
    const float* x    = (const float*)d_in[0];
    const float* woff = (const float*)d_in[1];
    const float* wdef = (const float*)d_in[2];
    float* out  = (float*)d_out;

    unsigned short* wfrag = (unsigned short*)d_ws;          // 73.7 KB
    unsigned short* wfo   = wfrag + 36864;                  // 36.9 KB
    unsigned short* xT    = wfo + 18432;                    // 16.8 MB

    hipLaunchKernelGGL(to_chlast_k, dim3(BATCH * HH), dim3(256), 0, stream,
                       x, xT);
    hipLaunchKernelGGL(build_w_k, dim3((36864 + 18432 + 255) / 256), dim3(256), 0, stream,
                       wdef, woff, wfrag, wfo);
    hipLaunchKernelGGL(deform_fused8_k, dim3((HH / 2) * 2 * 8), dim3(512), 0, stream,
                       xT, (const half8*)wfo, (const half8*)wfrag, out);
}